// Round 10
// baseline (124.225 us; speedup 1.0000x reference)
//
#include <hip/hip_runtime.h>

// ============================================================================
// AttentionWithSpatial: x@Wqkv -> masked/biased 4-head attention -> @Wout+b
// b=4, n=2048, dim=256, heads=4, dhead=64, scale=0.125
//
// R9 post-mortem: k_attn 59us, VALU 58% / LDS ~54% both unsaturated at 4
// blocks/CU (grid-capped) -> latency gaps. R10:
//  - KV-split=4: grid 2048 -> 7-8 blocks/CU (28 waves/CU). Partials:
//    Op0<-xh/xl, Op1<-d_out, Op2/Op3 fresh (+16MB); MP/LP fresh 512KB each.
//  - bias as MFMA accumulator INIT (8 fp16 cvts, no adds) - 8 VALU/iter saved.
//  - k_comb: exact 4-way flash merge.
//  - k_prep/k_qkv/k_out identical to passing R9.
// ============================================================================

#define B_   4
#define N_   2048
#define H_   4
#define DH_  64
#define DIMX 256
#define M_   (B_*N_)   // 8192

#define LOG2E  1.4426950408889634f
#define NEGINF (-1e30f)
#define DEFER_THR 8.0f

typedef __attribute__((ext_vector_type(8))) short short8;
typedef __attribute__((ext_vector_type(4))) float f32x4;
typedef unsigned short u16;
typedef unsigned int   u32;

#define MFMA16(a,b,c) __builtin_amdgcn_mfma_f32_16x16x32_bf16((a),(b),(c),0,0,0)

__device__ __forceinline__ u16 f2bf(float f) {
  u32 u = __builtin_bit_cast(u32, f);
  u += 0x7fffu + ((u >> 16) & 1u);   // RNE
  return (u16)(u >> 16);
}
__device__ __forceinline__ float bf2f(u16 h) {
  u32 u = ((u32)h) << 16;
  return __builtin_bit_cast(float, u);
}
__device__ __forceinline__ void split2(float f, u16* hi, u16* lo) {
  u16 h = f2bf(f);
  *hi = h;
  *lo = f2bf(f - bf2f(h));
}
__device__ __forceinline__ float bpermf(int srclane, float v) {
  return __builtin_bit_cast(float,
      __builtin_amdgcn_ds_bpermute(srclane << 2, __builtin_bit_cast(int, v)));
}
__device__ __forceinline__ u32 cvtpk(float lo, float hi) {
  u32 r;
  asm("v_cvt_pk_bf16_f32 %0, %1, %2" : "=v"(r) : "v"(lo), "v"(hi));
  return r;
}

struct u16v4 { u16 a, b, c, d; };
struct u16v8 { u16 v[8]; };

// ---------------------------------------------------------------------------
// Kernel 1 (fused prep):
//  blocks [0,8192): bias prefuse  mask? spat*log2e : -1e4  -> fp16 frag-major
//  blocks [8192,11264): x -> xh/xl split; Wqkv/Wout transpose+split
// ---------------------------------------------------------------------------
__global__ __launch_bounds__(256) void k_prep(
    const int* __restrict__ mask, const float* __restrict__ spat,
    const float* __restrict__ x, const float* __restrict__ wq,
    const float* __restrict__ wo,
    u16* __restrict__ biasF,
    u16* __restrict__ xh, u16* __restrict__ xl,
    u16* __restrict__ wqh, u16* __restrict__ wql,
    u16* __restrict__ woh, u16* __restrict__ wol)
{
  if (blockIdx.x < 8192) {
    const int r = blockIdx.x * 256 + threadIdx.x;     // [0, 2097152)
    const int lane = r & 63;
    const int kt = (r >> 6) & 63;
    const int qt = (r >> 12) & 127;
    const int b  = r >> 19;
    const int ln = lane & 15, hb = lane >> 4;
    const int q  = qt * 16 + ln;
    const int c0 = kt * 32 + hb * 4;
    const int base = (b * N_ + q) * N_ + c0;

    const int4   m0 = *(const int4*)&mask[base];
    const int4   m1 = *(const int4*)&mask[base + 16];
    const float4 s0 = *(const float4*)&spat[base];
    const float4 s1 = *(const float4*)&spat[base + 16];

    const float NB = -10000.0f;
    u16v8 o;
    o.v[0] = __builtin_bit_cast(u16, (_Float16)(m0.x ? s0.x * LOG2E : NB));
    o.v[1] = __builtin_bit_cast(u16, (_Float16)(m0.y ? s0.y * LOG2E : NB));
    o.v[2] = __builtin_bit_cast(u16, (_Float16)(m0.z ? s0.z * LOG2E : NB));
    o.v[3] = __builtin_bit_cast(u16, (_Float16)(m0.w ? s0.w * LOG2E : NB));
    o.v[4] = __builtin_bit_cast(u16, (_Float16)(m1.x ? s1.x * LOG2E : NB));
    o.v[5] = __builtin_bit_cast(u16, (_Float16)(m1.y ? s1.y * LOG2E : NB));
    o.v[6] = __builtin_bit_cast(u16, (_Float16)(m1.z ? s1.z * LOG2E : NB));
    o.v[7] = __builtin_bit_cast(u16, (_Float16)(m1.w ? s1.w * LOG2E : NB));
    *(u16v8*)&biasF[(size_t)r * 8] = o;
    return;
  }

  const int NX4 = (M_ * DIMX) / 4;  // 524288
  const int NWQ = 768 * 256;        // 196608
  const int NWO = 256 * 256;        // 65536
  int i = (blockIdx.x - 8192) * 256 + threadIdx.x;
  if (i < NX4) {
    const float4 v = ((const float4*)x)[i];
    u16v4 hv, lv;
    split2(v.x, &hv.a, &lv.a);
    split2(v.y, &hv.b, &lv.b);
    split2(v.z, &hv.c, &lv.c);
    split2(v.w, &hv.d, &lv.d);
    ((u16v4*)xh)[i] = hv;
    ((u16v4*)xl)[i] = lv;
  } else if (i < NX4 + NWQ) {
    int j = i - NX4;
    int c = j >> 8, k = j & 255;            // out layout [c][k]
    split2(wq[k * 768 + c], &wqh[j], &wql[j]);
  } else if (i < NX4 + NWQ + NWO) {
    int j = i - NX4 - NWQ;
    int c = j >> 8, k = j & 255;
    split2(wo[k * 256 + c], &woh[j], &wol[j]);
  }
}

// ---------------------------------------------------------------------------
// Kernel 2: QKV GEMM, LDS-staged. M=8192, N=768, K=256. grid (12, 64).
// B tile (hi+lo) staged once in 64KB LDS, XOR-swizzled; 2 M-subtiles/block;
// 16 A loads upfront per subtile; MFMA fed from LDS.
// ---------------------------------------------------------------------------
__global__ __launch_bounds__(256) void k_qkv(
    const u16* __restrict__ xh, const u16* __restrict__ xl,
    const u16* __restrict__ wh, const u16* __restrict__ wl,
    u16* __restrict__ qh, u16* __restrict__ ql,
    u16* __restrict__ kf, u16* __restrict__ vf)
{
  __shared__ __align__(16) u16 BhL[64 * 256];   // 32 KB, swizzled
  __shared__ __align__(16) u16 BlL[64 * 256];   // 32 KB

  const int tid = threadIdx.x;
  const int w = tid >> 6, lane = tid & 63;
  const int ln = lane & 15, hb = lane >> 4;
  const int colb = blockIdx.x * 64;

  // ---- stage B (hi+lo) into LDS, reg-batched, coalesced ----
  {
    short8 sb[16];
#pragma unroll
    for (int it = 0; it < 8; ++it) {
      const int c = it * 8 + (tid >> 5), k8 = tid & 31;
      sb[it]     = *(const short8*)&wh[(colb + c) * 256 + k8 * 8];
      sb[8 + it] = *(const short8*)&wl[(colb + c) * 256 + k8 * 8];
    }
#pragma unroll
    for (int it = 0; it < 8; ++it) {
      const int c = it * 8 + (tid >> 5), k8 = tid & 31;
      const int le = c * 256 + ((k8 * 8) ^ ((c & 7) << 3));
      *(short8*)&BhL[le] = sb[it];
      *(short8*)&BlL[le] = sb[8 + it];
    }
  }
  __syncthreads();

#pragma unroll
  for (int st = 0; st < 2; ++st) {
    const int mtile = blockIdx.y * 2 + st;
    const int arow = mtile * 64 + w * 16 + ln;

    short8 a_h8[8], a_l8[8];
#pragma unroll
    for (int ks = 0; ks < 8; ++ks) {
      a_h8[ks] = *(const short8*)&xh[arow * 256 + ks * 32 + hb * 8];
      a_l8[ks] = *(const short8*)&xl[arow * 256 + ks * 32 + hb * 8];
    }

    f32x4 acc[4] = {};
#pragma unroll
    for (int ks = 0; ks < 8; ++ks) {
      const int k0 = ks * 32 + hb * 8;
#pragma unroll
      for (int j = 0; j < 4; ++j) {
        const int c = j * 16 + ln;
        const int le = c * 256 + (k0 ^ ((c & 7) << 3));
        const short8 b_h = *(const short8*)&BhL[le];
        const short8 b_l = *(const short8*)&BlL[le];
        acc[j] = MFMA16(a_h8[ks], b_h, acc[j]);
        acc[j] = MFMA16(a_l8[ks], b_h, acc[j]);
        acc[j] = MFMA16(a_h8[ks], b_l, acc[j]);
      }
    }

    const int mbase = mtile * 64 + w * 16 + hb * 4;
#pragma unroll
    for (int j = 0; j < 4; ++j) {
      const int c = colb + j * 16 + ln;
      const int which = c >> 8;        // 0=q 1=k 2=v
      const int hd = c & 255;
      const int hh = hd >> 6, d = hd & 63;
#pragma unroll
      for (int r = 0; r < 4; ++r) {
        const int m = mbase + r;
        const int bb = m >> 11, nn = m & 2047;
        const int bh = bb * H_ + hh;
        float v = acc[j][r];
        if (which == 0) {
          const int off = (bh * N_ + nn) * DH_ + d;
          v *= (0.125f * LOG2E);                 // scale + exp2-domain fold
          split2(v, &qh[off], &ql[off]);
        } else if (which == 1) {
          const int ktile = nn >> 5, jj = (nn >> 4) & 1, lnn = nn & 15;
          const int kc = d >> 5, hbb = (d >> 3) & 3, e = d & 7;
          const int off = (bh * 64 + ktile) * 2048 + (kc * 2 + jj) * 512
                        + (hbb * 16 + lnn) * 8 + e;
          kf[off] = f2bf(v);
        } else {
          const int ktile = nn >> 5, hbb = (nn >> 3) & 3, e = nn & 7;
          const int j2 = d >> 4, lnn = d & 15;
          const int off = (bh * 64 + ktile) * 2048 + j2 * 512
                        + (hbb * 16 + lnn) * 8 + e;
          vf[off] = f2bf(v);
        }
      }
    }
  }
}

// ---------------------------------------------------------------------------
// Kernel 3: flash attention partials, KV-split=4. grid 2048:
// bid = qq*64 + bh*4 + s; 4 waves = 4 q-tiles of SAME head share K/V in LDS
// (dbuf, 1 barrier/iter). Each block covers kt in [s*16, s*16+16).
// Bias is the MFMA accumulator init. Writes unnormalized O + m,l per split.
// ---------------------------------------------------------------------------
__global__ __launch_bounds__(256) void k_attn(
    const u16* __restrict__ qhg, const u16* __restrict__ qlg,
    const u16* __restrict__ kfg, const u16* __restrict__ vfg,
    const u16* __restrict__ biasF,
    float* __restrict__ Op0, float* __restrict__ Op1,
    float* __restrict__ Op2, float* __restrict__ Op3,
    float* __restrict__ MP, float* __restrict__ LP)
{
  __shared__ __align__(16) u16 KL[2][2048];    // 8 KB  (32x64 bf16 tile)
  __shared__ __align__(16) u16 VL[2][2048];    // 8 KB  (V^T fragments)
  __shared__ __align__(16) u32 Pbuf[4][320];   // 5 KB, per-wave P exchange

  const int bid = blockIdx.x;
  const int s  = bid & 3;                      // kv split index
  const int bh = (bid >> 2) & 15;
  const int qq = bid >> 6;
  const int b = bh >> 2, h = bh & 3;
  const int kt0 = s * 16;

  const int tid = threadIdx.x;
  const int w = tid >> 6, lane = tid & 63;
  const int qt = qq * 4 + w;                   // this wave's q-tile [0,128)
  const int ln = lane & 15, hb = lane >> 4;

  // ---- Q fragments (pre-scaled by 0.125*log2e), hi/lo ----
  short8 qfh[2], qfl[2];
  {
    const int base = ((b * H_ + h) * N_ + qt * 16 + ln) * DH_;
    qfh[0] = *(const short8*)&qhg[base + hb * 8];
    qfh[1] = *(const short8*)&qhg[base + 32 + hb * 8];
    qfl[0] = *(const short8*)&qlg[base + hb * 8];
    qfl[1] = *(const short8*)&qlg[base + 32 + hb * 8];
  }

  const u16* Kt0 = kfg + (size_t)((b * H_ + h) * 64) * 2048;
  const u16* Vt0 = vfg + (size_t)((b * H_ + h) * 64) * 2048;
  const u16* Bt0 = biasF + (size_t)((b * 128 + qt) * 64) * 512;
  const int stoff = w * 512 + lane * 8;  // this thread's staging slot (16B)
  const int l8 = lane * 8;

  short8 ones;
#pragma unroll
  for (int i = 0; i < 8; ++i) ones[i] = (short)0x3F80;   // bf16 1.0

  f32x4 O[4] = {};
  f32x4 l_acc = {};
  float m_run = NEGINF;
  u32* Pw = &Pbuf[w][0];

  short8 kst, vst, bc, bn;

  // ---- prologue: stage tile kt0, load bias kt0 ----
  kst = *(const short8*)&Kt0[kt0 * 2048 + stoff];
  vst = *(const short8*)&Vt0[kt0 * 2048 + stoff];
  bc  = *(const short8*)&Bt0[kt0 * 512 + l8];
  *(short8*)&KL[0][stoff] = kst;
  *(short8*)&VL[0][stoff] = vst;
  __syncthreads();

  int cur = 0;
  for (int it = 0; it < 16; ++it) {
    const int ktn = kt0 + ((it + 1) & 15);

    // ---- issue next-tile loads early (hide HBM/L2 latency under compute) --
    kst = *(const short8*)&Kt0[ktn * 2048 + stoff];
    vst = *(const short8*)&Vt0[ktn * 2048 + stoff];
    bn  = *(const short8*)&Bt0[ktn * 512 + l8];

    // ---- swapped QK^T from LDS, accumulator initialized with the bias ----
    f32x4 dots[2];
#pragma unroll
    for (int j = 0; j < 2; ++j)
#pragma unroll
      for (int r = 0; r < 4; ++r)
        dots[j][r] = (float)__builtin_bit_cast(_Float16, (u16)bc[j * 4 + r]);
    __builtin_amdgcn_s_setprio(1);
#pragma unroll
    for (int kc = 0; kc < 2; ++kc)
#pragma unroll
      for (int j = 0; j < 2; ++j) {
        const short8 kfr = *(const short8*)&KL[cur][(kc * 2 + j) * 512 + l8];
        dots[j] = MFMA16(kfr, qfh[kc], dots[j]);
        dots[j] = MFMA16(kfr, qfl[kc], dots[j]);
      }
    __builtin_amdgcn_s_setprio(0);

    // ---- per-lane online softmax (q=ln), defer-max THR=8 ----
    float pmax = fmaxf(
        fmaxf(fmaxf(dots[0][0], dots[0][1]), fmaxf(dots[0][2], dots[0][3])),
        fmaxf(fmaxf(dots[1][0], dots[1][1]), fmaxf(dots[1][2], dots[1][3])));
    pmax = fmaxf(pmax, __shfl_xor(pmax, 16));
    pmax = fmaxf(pmax, __shfl_xor(pmax, 32));
    if (__any(pmax > m_run + DEFER_THR)) {
      const float mn = fmaxf(m_run, pmax);
      const float fac = exp2f(m_run - mn);
      m_run = mn;
#pragma unroll
      for (int r = 0; r < 4; ++r) {
        const float fr = bpermf(hb * 4 + r, fac);
        O[0][r] *= fr; O[1][r] *= fr; O[2][r] *= fr; O[3][r] *= fr;
        l_acc[r] *= fr;
      }
    }
    float p[2][4];
#pragma unroll
    for (int j = 0; j < 2; ++j)
#pragma unroll
      for (int r = 0; r < 4; ++r)
        p[j][r] = exp2f(dots[j][r] - m_run);

    // ---- pack bf16 + exchange to A-fragment via per-wave LDS ----
    {
      uint2 w0, w1;
      w0.x = cvtpk(p[0][0], p[0][1]); w0.y = cvtpk(p[0][2], p[0][3]);
      w1.x = cvtpk(p[1][0], p[1][1]); w1.y = cvtpk(p[1][2], p[1][3]);
      *(uint2*)&Pw[ln * 20 + hb * 2]     = w0;
      *(uint2*)&Pw[ln * 20 + 8 + hb * 2] = w1;
    }
    const short8 pf = *(const short8*)&Pw[ln * 20 + hb * 4];

    // ---- PV + row-sum via ones-MFMA (V frags from LDS) ----
    __builtin_amdgcn_s_setprio(1);
#pragma unroll
    for (int j2 = 0; j2 < 4; ++j2) {
      const short8 vfr = *(const short8*)&VL[cur][j2 * 512 + l8];
      O[j2] = MFMA16(pf, vfr, O[j2]);
    }
    l_acc = MFMA16(pf, ones, l_acc);
    __builtin_amdgcn_s_setprio(0);

    // ---- write staged tile into the other buffer (late write, T14) ----
    *(short8*)&KL[cur ^ 1][stoff] = kst;
    *(short8*)&VL[cur ^ 1][stoff] = vst;
    __syncthreads();
    bc = bn;
    cur ^= 1;
  }

  // ---- epilogue: write unnormalized partial O + per-row m,l ----
  const int gg = (b * H_ + h) * 128 + qt;          // [0, 2048)
  const int g  = gg * 4 + s;                       // MP/LP index
  float* Opg = (s == 0 ? Op0 : s == 1 ? Op1 : s == 2 ? Op2 : Op3)
             + (size_t)gg * 1024;
#pragma unroll
  for (int j2 = 0; j2 < 4; ++j2)
#pragma unroll
    for (int r = 0; r < 4; ++r)
      Opg[(hb * 4 + r) * 64 + j2 * 16 + ln] = O[j2][r];
  if (lane < 16) MP[g * 16 + lane] = m_run;       // hb=0, q=ln
  if (ln == 0) {
#pragma unroll
    for (int r = 0; r < 4; ++r) LP[g * 16 + hb * 4 + r] = l_acc[r];
  }
}

// ---------------------------------------------------------------------------
// Kernel 3b: exact 4-way flash merge, normalize, write split-bf16 attn-out.
// grid 1024 x 256; thread -> (row, 8 cols).
// ---------------------------------------------------------------------------
__global__ __launch_bounds__(256) void k_comb(
    const float* __restrict__ Op0, const float* __restrict__ Op1,
    const float* __restrict__ Op2, const float* __restrict__ Op3,
    const float* __restrict__ MP, const float* __restrict__ LP,
    u16* __restrict__ ah, u16* __restrict__ al)
{
  const int i = blockIdx.x * 256 + threadIdx.x;   // [0, 262144)
  const int row = i >> 5, cg = i & 31;
  const int c0 = cg * 8, h = c0 >> 6, d0 = c0 & 63;
  const int b = row >> 11, nn = row & 2047, qt = nn >> 4, q = nn & 15;
  const int gg = (b * H_ + h) * 128 + qt;
  const int g0 = gg * 4;

  const float m0 = MP[(g0 + 0) * 16 + q], m1 = MP[(g0 + 1) * 16 + q];
  const float m2 = MP[(g0 + 2) * 16 + q], m3 = MP[(g0 + 3) * 16 + q];
  const float mm = fmaxf(fmaxf(m0, m1), fmaxf(m2, m3));
  const float f0 = exp2f(m0 - mm), f1 = exp2f(m1 - mm);
  const float f2 = exp2f(m2 - mm), f3 = exp2f(m3 - mm);
  const float l = LP[(g0 + 0) * 16 + q] * f0 + LP[(g0 + 1) * 16 + q] * f1
                + LP[(g0 + 2) * 16 + q] * f2 + LP[(g0 + 3) * 16 + q] * f3;
  const float inv = 1.0f / l;

  const size_t po = (size_t)gg * 1024 + q * 64 + d0;
  const float* p0 = Op0 + po;
  const float* p1 = Op1 + po;
  const float* p2 = Op2 + po;
  const float* p3 = Op3 + po;

  u16v8 hh, ll;
#pragma unroll
  for (int half = 0; half < 2; ++half) {
    const f32x4 a0 = *(const f32x4*)(p0 + half * 4);
    const f32x4 a1 = *(const f32x4*)(p1 + half * 4);
    const f32x4 a2 = *(const f32x4*)(p2 + half * 4);
    const f32x4 a3 = *(const f32x4*)(p3 + half * 4);
#pragma unroll
    for (int e = 0; e < 4; ++e) {
      const float v = (a0[e] * f0 + a1[e] * f1 + a2[e] * f2 + a3[e] * f3) * inv;
      split2(v, &hh.v[half * 4 + e], &ll.v[half * 4 + e]);
    }
  }
  *(u16v8*)&ah[row * DIMX + c0] = hh;
  *(u16v8*)&al[row * DIMX + c0] = ll;
}

// ---------------------------------------------------------------------------
// Kernel 4: out = aout @ Wout + b_out, LDS-staged. M=8192, N=256, K=256.
// grid (4, 64): colb = bx*64; 2 M-subtiles per block; B hi+lo in 64KB LDS.
// ---------------------------------------------------------------------------
__global__ __launch_bounds__(256) void k_out(
    const u16* __restrict__ ahg, const u16* __restrict__ alg,
    const u16* __restrict__ wh, const u16* __restrict__ wl,
    const float* __restrict__ bout, float* __restrict__ out)
{
  __shared__ __align__(16) u16 BhL[64 * 256];   // 32 KB, swizzled
  __shared__ __align__(16) u16 BlL[64 * 256];   // 32 KB

  const int tid = threadIdx.x;
  const int w = tid >> 6, lane = tid & 63;
  const int ln = lane & 15, hb = lane >> 4;
  const int colb = blockIdx.x * 64;

  // ---- stage B (hi+lo) into LDS ----
  {
    short8 sb[16];
#pragma unroll
    for (int it = 0; it < 8; ++it) {
      const int c = it * 8 + (tid >> 5), k8 = tid & 31;
      sb[it]     = *(const short8*)&wh[(colb + c) * 256 + k8 * 8];
      sb[8 + it] = *(const short8*)&wl[(colb + c) * 256 + k8 * 8];
    }
#pragma unroll
    for (int it = 0; it < 8; ++it) {
      const int c = it * 8 + (tid >> 5), k8 = tid & 31;
      const int le = c * 256 + ((k8 * 8) ^ ((c & 7) << 3));
      *(short8*)&BhL[le] = sb[it];
      *(short8*)&BlL[le] = sb[8 + it];
    }
  }
  __syncthreads();

#pragma unroll
  for (int st = 0; st < 2; ++st) {
    const int mtile = blockIdx.y * 2 + st;
    const int arow = mtile * 64 + w * 16 + ln;

    short8 a_h8[8], a_l8[8];
#pragma unroll
    for (int ks = 0; ks < 8; ++ks) {
      a_h8[ks] = *(const short8*)&ahg[arow * 256 + ks * 32 + hb * 8];
      a_l8[ks] = *(const short8*)&alg[arow * 256 + ks * 32 + hb * 8];
    }

    f32x4 acc[4] = {};
#pragma unroll
    for (int ks = 0; ks < 8; ++ks) {
      const int k0 = ks * 32 + hb * 8;
#pragma unroll
      for (int j = 0; j < 4; ++j) {
        const int c = j * 16 + ln;
        const int le = c * 256 + (k0 ^ ((c & 7) << 3));
        const short8 b_h = *(const short8*)&BhL[le];
        const short8 b_l = *(const short8*)&BlL[le];
        acc[j] = MFMA16(a_h8[ks], b_h, acc[j]);
        acc[j] = MFMA16(a_l8[ks], b_h, acc[j]);
        acc[j] = MFMA16(a_h8[ks], b_l, acc[j]);
      }
    }

    const int mbase = mtile * 64 + w * 16 + hb * 4;
#pragma unroll
    for (int j = 0; j < 4; ++j) {
      const int c = colb + j * 16 + ln;
      const float bb = bout[c];
#pragma unroll
      for (int r = 0; r < 4; ++r)
        out[(mbase + r) * 256 + c] = acc[j][r] + bb;
    }
  }
}

// ---------------------------------------------------------------------------
extern "C" void kernel_launch(void* const* d_in, const int* in_sizes, int n_in,
                              void* d_out, int out_size, void* d_ws, size_t ws_size,
                              hipStream_t stream)
{
  (void)in_sizes; (void)n_in; (void)out_size; (void)ws_size;
  const float* x    = (const float*)d_in[0];
  const int*   mask = (const int*)d_in[1];
  const float* spat = (const float*)d_in[2];
  const float* wq   = (const float*)d_in[3];
  const float* wo   = (const float*)d_in[4];
  const float* bout = (const float*)d_in[5];
  float* out = (float*)d_out;

  char* ws = (char*)d_ws;
  size_t o = 0;
  auto alloc = [&](size_t bytes) -> char* {
    char* p = ws + o;
    o += (bytes + 255) & ~(size_t)255;
    return p;
  };
  u16* xh  = (u16*)alloc((size_t)M_ * 256 * 2);   // 4 MB  \ Op0 alias (8 MB)
  u16* xl  = (u16*)alloc((size_t)M_ * 256 * 2);   // 4 MB  /
  u16* wqh = (u16*)alloc((size_t)768 * 256 * 2);
  u16* wql = (u16*)alloc((size_t)768 * 256 * 2);
  u16* woh = (u16*)alloc((size_t)256 * 256 * 2);
  u16* wol = (u16*)alloc((size_t)256 * 256 * 2);
  u16* qh  = (u16*)alloc((size_t)16 * N_ * DH_ * 2);
  u16* ql  = (u16*)alloc((size_t)16 * N_ * DH_ * 2);
  u16* kf  = (u16*)alloc((size_t)16 * N_ * DH_ * 2);
  u16* vf  = (u16*)alloc((size_t)16 * N_ * DH_ * 2);
  u16* ah  = (u16*)alloc((size_t)M_ * 256 * 2);
  u16* al  = (u16*)alloc((size_t)M_ * 256 * 2);
  u16* biasF = (u16*)alloc((size_t)4 * 128 * 64 * 512 * 2);  // 33.5 MB fp16
  float* Op2 = (float*)alloc((size_t)2048 * 1024 * 4);       // 8 MB
  float* Op3 = (float*)alloc((size_t)2048 * 1024 * 4);       // 8 MB
  float* MP  = (float*)alloc((size_t)8192 * 16 * 4);         // 512 KB
  float* LP  = (float*)alloc((size_t)8192 * 16 * 4);         // 512 KB

  // Aliases (dead by the time they're written):
  //  Op0 (8,388,608 B) <- xh+xl (contiguous, dead after k_qkv)
  //  Op1 (8,388,608 B) <- d_out (8192*256*4, fully overwritten by k_out)
  float* Op0 = (float*)xh;
  float* Op1 = out;

  hipLaunchKernelGGL(k_prep, dim3(11264), dim3(256), 0, stream,
                     mask, spat, x, wq, wo, biasF,
                     xh, xl, wqh, wql, woh, wol);
  hipLaunchKernelGGL(k_qkv, dim3(12, 64), dim3(256), 0, stream,
                     xh, xl, wqh, wql, qh, ql, kf, vf);
  hipLaunchKernelGGL(k_attn, dim3(2048), dim3(256), 0, stream,
                     qh, ql, kf, vf, biasF, Op0, Op1, Op2, Op3, MP, LP);
  hipLaunchKernelGGL(k_comb, dim3(1024), dim3(256), 0, stream,
                     Op0, Op1, Op2, Op3, MP, LP, ah, al);
  hipLaunchKernelGGL(k_out, dim3(4, 64), dim3(256), 0, stream,
                     ah, al, woh, wol, bout, out);
}

// Round 11
// 123.144 us; speedup vs baseline: 1.0088x; 1.0088x over previous
//
#include <hip/hip_runtime.h>

// ============================================================================
// AttentionWithSpatial: x@Wqkv -> masked/biased 4-head attention -> @Wout+b
// b=4, n=2048, dim=256, heads=4, dhead=64, scale=0.125
//
// R10 post-mortem: k_attn throughput invariant to TLP (16 vs 28 waves/CU ->
// same 59us) => per-iteration instruction/chain bound. R11:
//  - PV operand swap: mfma(V_Afrag, P_Bfrag) -> O is [d][q], q lane-local:
//    rescale has NO bpermutes; l_acc via mfma(ones,P) lane-local.
//  - KVBLK=64: one softmax pass / P-exchange / trigger-check per 64 keys;
//    loop overhead halved. LDS 25KB (K 8 + V 8 + P 9), 6 blocks/CU.
//  - KV-split back to 2 (split=4 gained nothing, cost k_comb traffic).
//  - k_prep/k_qkv/k_out identical to R10; R9 alias scheme (proven).
// ============================================================================

#define B_   4
#define N_   2048
#define H_   4
#define DH_  64
#define DIMX 256
#define M_   (B_*N_)   // 8192

#define LOG2E  1.4426950408889634f
#define NEGINF (-1e30f)
#define DEFER_THR 8.0f

typedef __attribute__((ext_vector_type(8))) short short8;
typedef __attribute__((ext_vector_type(4))) float f32x4;
typedef unsigned short u16;
typedef unsigned int   u32;

#define MFMA16(a,b,c) __builtin_amdgcn_mfma_f32_16x16x32_bf16((a),(b),(c),0,0,0)

__device__ __forceinline__ u16 f2bf(float f) {
  u32 u = __builtin_bit_cast(u32, f);
  u += 0x7fffu + ((u >> 16) & 1u);   // RNE
  return (u16)(u >> 16);
}
__device__ __forceinline__ float bf2f(u16 h) {
  u32 u = ((u32)h) << 16;
  return __builtin_bit_cast(float, u);
}
__device__ __forceinline__ void split2(float f, u16* hi, u16* lo) {
  u16 h = f2bf(f);
  *hi = h;
  *lo = f2bf(f - bf2f(h));
}
__device__ __forceinline__ u32 cvtpk(float lo, float hi) {
  u32 r;
  asm("v_cvt_pk_bf16_f32 %0, %1, %2" : "=v"(r) : "v"(lo), "v"(hi));
  return r;
}

struct u16v4 { u16 a, b, c, d; };
struct u16v8 { u16 v[8]; };

// ---------------------------------------------------------------------------
// Kernel 1 (fused prep):
//  blocks [0,8192): bias prefuse  mask? spat*log2e : -1e4  -> fp16 frag-major
//  blocks [8192,11264): x -> xh/xl split; Wqkv/Wout transpose+split
// ---------------------------------------------------------------------------
__global__ __launch_bounds__(256) void k_prep(
    const int* __restrict__ mask, const float* __restrict__ spat,
    const float* __restrict__ x, const float* __restrict__ wq,
    const float* __restrict__ wo,
    u16* __restrict__ biasF,
    u16* __restrict__ xh, u16* __restrict__ xl,
    u16* __restrict__ wqh, u16* __restrict__ wql,
    u16* __restrict__ woh, u16* __restrict__ wol)
{
  if (blockIdx.x < 8192) {
    const int r = blockIdx.x * 256 + threadIdx.x;     // [0, 2097152)
    const int lane = r & 63;
    const int kt = (r >> 6) & 63;
    const int qt = (r >> 12) & 127;
    const int b  = r >> 19;
    const int ln = lane & 15, hb = lane >> 4;
    const int q  = qt * 16 + ln;
    const int c0 = kt * 32 + hb * 4;
    const int base = (b * N_ + q) * N_ + c0;

    const int4   m0 = *(const int4*)&mask[base];
    const int4   m1 = *(const int4*)&mask[base + 16];
    const float4 s0 = *(const float4*)&spat[base];
    const float4 s1 = *(const float4*)&spat[base + 16];

    const float NB = -10000.0f;
    u16v8 o;
    o.v[0] = __builtin_bit_cast(u16, (_Float16)(m0.x ? s0.x * LOG2E : NB));
    o.v[1] = __builtin_bit_cast(u16, (_Float16)(m0.y ? s0.y * LOG2E : NB));
    o.v[2] = __builtin_bit_cast(u16, (_Float16)(m0.z ? s0.z * LOG2E : NB));
    o.v[3] = __builtin_bit_cast(u16, (_Float16)(m0.w ? s0.w * LOG2E : NB));
    o.v[4] = __builtin_bit_cast(u16, (_Float16)(m1.x ? s1.x * LOG2E : NB));
    o.v[5] = __builtin_bit_cast(u16, (_Float16)(m1.y ? s1.y * LOG2E : NB));
    o.v[6] = __builtin_bit_cast(u16, (_Float16)(m1.z ? s1.z * LOG2E : NB));
    o.v[7] = __builtin_bit_cast(u16, (_Float16)(m1.w ? s1.w * LOG2E : NB));
    *(u16v8*)&biasF[(size_t)r * 8] = o;
    return;
  }

  const int NX4 = (M_ * DIMX) / 4;  // 524288
  const int NWQ = 768 * 256;        // 196608
  const int NWO = 256 * 256;        // 65536
  int i = (blockIdx.x - 8192) * 256 + threadIdx.x;
  if (i < NX4) {
    const float4 v = ((const float4*)x)[i];
    u16v4 hv, lv;
    split2(v.x, &hv.a, &lv.a);
    split2(v.y, &hv.b, &lv.b);
    split2(v.z, &hv.c, &lv.c);
    split2(v.w, &hv.d, &lv.d);
    ((u16v4*)xh)[i] = hv;
    ((u16v4*)xl)[i] = lv;
  } else if (i < NX4 + NWQ) {
    int j = i - NX4;
    int c = j >> 8, k = j & 255;            // out layout [c][k]
    split2(wq[k * 768 + c], &wqh[j], &wql[j]);
  } else if (i < NX4 + NWQ + NWO) {
    int j = i - NX4 - NWQ;
    int c = j >> 8, k = j & 255;
    split2(wo[k * 256 + c], &woh[j], &wol[j]);
  }
}

// ---------------------------------------------------------------------------
// Kernel 2: QKV GEMM, LDS-staged. M=8192, N=768, K=256. grid (12, 64).
// B tile (hi+lo) staged once in 64KB LDS, XOR-swizzled; 2 M-subtiles/block;
// 16 A loads upfront per subtile; MFMA fed from LDS.
// ---------------------------------------------------------------------------
__global__ __launch_bounds__(256) void k_qkv(
    const u16* __restrict__ xh, const u16* __restrict__ xl,
    const u16* __restrict__ wh, const u16* __restrict__ wl,
    u16* __restrict__ qh, u16* __restrict__ ql,
    u16* __restrict__ kf, u16* __restrict__ vf)
{
  __shared__ __align__(16) u16 BhL[64 * 256];   // 32 KB, swizzled
  __shared__ __align__(16) u16 BlL[64 * 256];   // 32 KB

  const int tid = threadIdx.x;
  const int w = tid >> 6, lane = tid & 63;
  const int ln = lane & 15, hb = lane >> 4;
  const int colb = blockIdx.x * 64;

  // ---- stage B (hi+lo) into LDS, reg-batched, coalesced ----
  {
    short8 sb[16];
#pragma unroll
    for (int it = 0; it < 8; ++it) {
      const int c = it * 8 + (tid >> 5), k8 = tid & 31;
      sb[it]     = *(const short8*)&wh[(colb + c) * 256 + k8 * 8];
      sb[8 + it] = *(const short8*)&wl[(colb + c) * 256 + k8 * 8];
    }
#pragma unroll
    for (int it = 0; it < 8; ++it) {
      const int c = it * 8 + (tid >> 5), k8 = tid & 31;
      const int le = c * 256 + ((k8 * 8) ^ ((c & 7) << 3));
      *(short8*)&BhL[le] = sb[it];
      *(short8*)&BlL[le] = sb[8 + it];
    }
  }
  __syncthreads();

#pragma unroll
  for (int st = 0; st < 2; ++st) {
    const int mtile = blockIdx.y * 2 + st;
    const int arow = mtile * 64 + w * 16 + ln;

    short8 a_h8[8], a_l8[8];
#pragma unroll
    for (int ks = 0; ks < 8; ++ks) {
      a_h8[ks] = *(const short8*)&xh[arow * 256 + ks * 32 + hb * 8];
      a_l8[ks] = *(const short8*)&xl[arow * 256 + ks * 32 + hb * 8];
    }

    f32x4 acc[4] = {};
#pragma unroll
    for (int ks = 0; ks < 8; ++ks) {
      const int k0 = ks * 32 + hb * 8;
#pragma unroll
      for (int j = 0; j < 4; ++j) {
        const int c = j * 16 + ln;
        const int le = c * 256 + (k0 ^ ((c & 7) << 3));
        const short8 b_h = *(const short8*)&BhL[le];
        const short8 b_l = *(const short8*)&BlL[le];
        acc[j] = MFMA16(a_h8[ks], b_h, acc[j]);
        acc[j] = MFMA16(a_l8[ks], b_h, acc[j]);
        acc[j] = MFMA16(a_h8[ks], b_l, acc[j]);
      }
    }

    const int mbase = mtile * 64 + w * 16 + hb * 4;
#pragma unroll
    for (int j = 0; j < 4; ++j) {
      const int c = colb + j * 16 + ln;
      const int which = c >> 8;        // 0=q 1=k 2=v
      const int hd = c & 255;
      const int hh = hd >> 6, d = hd & 63;
#pragma unroll
      for (int r = 0; r < 4; ++r) {
        const int m = mbase + r;
        const int bb = m >> 11, nn = m & 2047;
        const int bh = bb * H_ + hh;
        float v = acc[j][r];
        if (which == 0) {
          const int off = (bh * N_ + nn) * DH_ + d;
          v *= (0.125f * LOG2E);                 // scale + exp2-domain fold
          split2(v, &qh[off], &ql[off]);
        } else if (which == 1) {
          const int ktile = nn >> 5, jj = (nn >> 4) & 1, lnn = nn & 15;
          const int kc = d >> 5, hbb = (d >> 3) & 3, e = d & 7;
          const int off = (bh * 64 + ktile) * 2048 + (kc * 2 + jj) * 512
                        + (hbb * 16 + lnn) * 8 + e;
          kf[off] = f2bf(v);
        } else {
          const int ktile = nn >> 5, hbb = (nn >> 3) & 3, e = nn & 7;
          const int j2 = d >> 4, lnn = d & 15;
          const int off = (bh * 64 + ktile) * 2048 + j2 * 512
                        + (hbb * 16 + lnn) * 8 + e;
          vf[off] = f2bf(v);
        }
      }
    }
  }
}

// ---------------------------------------------------------------------------
// Kernel 3: flash attention partials, KV-split=2, KVBLK=64. grid 1024:
// bid = qq*32 + bh*2 + half; 4 waves = 4 q-tiles of SAME head share K/V in
// LDS (single buffer of 2 kt-tiles, T14 reg-staged, 2 barriers/iter).
// Per iter (64 keys): QK^T (16 MFMA, bias-init), ONE softmax pass,
// ONE P-exchange, PV via operand-swap (O=[d][q], q lane-local -> rescale
// without bpermute). Writes unnormalized O + per-q m,l.
// ---------------------------------------------------------------------------
__global__ __launch_bounds__(256) void k_attn(
    const u16* __restrict__ qhg, const u16* __restrict__ qlg,
    const u16* __restrict__ kfg, const u16* __restrict__ vfg,
    const u16* __restrict__ biasF,
    float* __restrict__ Op0, float* __restrict__ Op1,
    float* __restrict__ MP, float* __restrict__ LP)
{
  __shared__ __align__(16) u16 KL[4096];       // 8 KB: 2 kt-tiles
  __shared__ __align__(16) u16 VL[4096];       // 8 KB: 2 kt-tiles (V^T frags)
  __shared__ __align__(16) u32 Pbuf[4][16 * 36]; // 9 KB: per-wave P exchange

  const int bid = blockIdx.x;
  const int half = bid & 1;
  const int bh = (bid >> 1) & 15;
  const int qq = bid >> 5;
  const int b = bh >> 2, h = bh & 3;
  const int kt0 = half * 32;                   // 32 kt-tiles = 16 iters of 2

  const int tid = threadIdx.x;
  const int w = tid >> 6, lane = tid & 63;
  const int qt = qq * 4 + w;                   // this wave's q-tile [0,128)
  const int ln = lane & 15, hb = lane >> 4;

  // ---- Q fragments (pre-scaled by 0.125*log2e), hi/lo ----
  short8 qfh[2], qfl[2];
  {
    const int base = ((b * H_ + h) * N_ + qt * 16 + ln) * DH_;
    qfh[0] = *(const short8*)&qhg[base + hb * 8];
    qfh[1] = *(const short8*)&qhg[base + 32 + hb * 8];
    qfl[0] = *(const short8*)&qlg[base + hb * 8];
    qfl[1] = *(const short8*)&qlg[base + 32 + hb * 8];
  }

  const u16* Kt0 = kfg + (size_t)((b * H_ + h) * 64) * 2048;
  const u16* Vt0 = vfg + (size_t)((b * H_ + h) * 64) * 2048;
  const u16* Bt0 = biasF + (size_t)((b * 128 + qt) * 64) * 512;
  const int stoff = tid * 8;             // staging slot: 16B per thread/tile
  const int l8 = lane * 8;

  short8 ones;
#pragma unroll
  for (int i = 0; i < 8; ++i) ones[i] = (short)0x3F80;   // bf16 1.0

  f32x4 O[4] = {};        // O[j2][r]: lane holds O[q=ln][d=j2*16+hb*4+r]
  f32x4 l_acc = {};       // all rows = l(q=ln)
  float m_run = NEGINF;   // per-lane, q=ln (uniform across hb group)
  u32* Pw = &Pbuf[w][0];

  short8 kn0, kn1, vn0, vn1, bc0, bc1, bn0, bn1;

  // ---- prologue: stage tiles kt0,kt0+1; load bias ----
  kn0 = *(const short8*)&Kt0[(kt0 + 0) * 2048 + stoff];
  kn1 = *(const short8*)&Kt0[(kt0 + 1) * 2048 + stoff];
  vn0 = *(const short8*)&Vt0[(kt0 + 0) * 2048 + stoff];
  vn1 = *(const short8*)&Vt0[(kt0 + 1) * 2048 + stoff];
  bc0 = *(const short8*)&Bt0[(kt0 + 0) * 512 + l8];
  bc1 = *(const short8*)&Bt0[(kt0 + 1) * 512 + l8];
  *(short8*)&KL[stoff]        = kn0;
  *(short8*)&KL[2048 + stoff] = kn1;
  *(short8*)&VL[stoff]        = vn0;
  *(short8*)&VL[2048 + stoff] = vn1;
  __syncthreads();

  for (int it = 0; it < 16; ++it) {
    const int ktn = kt0 + 2 * ((it + 1) & 15);

    // ---- issue next-iter loads early (hide latency under compute) ----
    kn0 = *(const short8*)&Kt0[(ktn + 0) * 2048 + stoff];
    kn1 = *(const short8*)&Kt0[(ktn + 1) * 2048 + stoff];
    vn0 = *(const short8*)&Vt0[(ktn + 0) * 2048 + stoff];
    vn1 = *(const short8*)&Vt0[(ktn + 1) * 2048 + stoff];
    bn0 = *(const short8*)&Bt0[(ktn + 0) * 512 + l8];
    bn1 = *(const short8*)&Bt0[(ktn + 1) * 512 + l8];

    // ---- QK^T over 64 keys, accumulator init = bias ----
    // dots[kt2*2+j][r] = S[k = kt2*32 + j*16 + hb*4 + r][q = ln]
    f32x4 dots[4];
#pragma unroll
    for (int jj = 0; jj < 4; ++jj) {
      const short8 bsrc = (jj < 2) ? bc0 : bc1;
      const int e0 = (jj & 1) * 4;
#pragma unroll
      for (int r = 0; r < 4; ++r)
        dots[jj][r] = (float)__builtin_bit_cast(_Float16, (u16)bsrc[e0 + r]);
    }
    __builtin_amdgcn_s_setprio(1);
#pragma unroll
    for (int kt2 = 0; kt2 < 2; ++kt2)
#pragma unroll
      for (int kc = 0; kc < 2; ++kc)
#pragma unroll
        for (int j = 0; j < 2; ++j) {
          const short8 kfr =
              *(const short8*)&KL[kt2 * 2048 + (kc * 2 + j) * 512 + l8];
          dots[kt2 * 2 + j] = MFMA16(kfr, qfh[kc], dots[kt2 * 2 + j]);
          dots[kt2 * 2 + j] = MFMA16(kfr, qfl[kc], dots[kt2 * 2 + j]);
        }
    __builtin_amdgcn_s_setprio(0);

    // ---- ONE softmax pass over 16 logits (q=ln), defer-max THR=8 ----
    float pmax = fmaxf(fmaxf(dots[0][0], dots[0][1]),
                       fmaxf(dots[0][2], dots[0][3]));
#pragma unroll
    for (int jj = 1; jj < 4; ++jj)
      pmax = fmaxf(pmax, fmaxf(fmaxf(dots[jj][0], dots[jj][1]),
                               fmaxf(dots[jj][2], dots[jj][3])));
    pmax = fmaxf(pmax, __shfl_xor(pmax, 16));
    pmax = fmaxf(pmax, __shfl_xor(pmax, 32));
    if (__any(pmax > m_run + DEFER_THR)) {
      const float mn = fmaxf(m_run, pmax);
      const float fac = exp2f(m_run - mn);     // lane-local (q=ln)
      m_run = mn;
#pragma unroll
      for (int j2 = 0; j2 < 4; ++j2) {
        O[j2][0] *= fac; O[j2][1] *= fac; O[j2][2] *= fac; O[j2][3] *= fac;
      }
      l_acc[0] *= fac; l_acc[1] *= fac; l_acc[2] *= fac; l_acc[3] *= fac;
    }
    float p[4][4];
#pragma unroll
    for (int jj = 0; jj < 4; ++jj)
#pragma unroll
      for (int r = 0; r < 4; ++r)
        p[jj][r] = exp2f(dots[jj][r] - m_run);

    // ---- ONE P-exchange: pack bf16, write row q=ln, read B-frags ----
#pragma unroll
    for (int jj = 0; jj < 4; ++jj) {
      uint2 wv;
      wv.x = cvtpk(p[jj][0], p[jj][1]);
      wv.y = cvtpk(p[jj][2], p[jj][3]);
      // k = (jj>>1)*32 + (jj&1)*16 + hb*4  -> u32 idx 16*(jj>>1)+8*(jj&1)+2*hb
      *(uint2*)&Pw[ln * 36 + (jj >> 1) * 16 + (jj & 1) * 8 + hb * 2] = wv;
    }
    const short8 pf0 = *(const short8*)&Pw[ln * 36 + hb * 4];        // k 0-31
    const short8 pf1 = *(const short8*)&Pw[ln * 36 + 16 + hb * 4];   // k 32-63

    // ---- PV operand-swapped: O[j2] += V_A x P_B ; l += ones x P ----
    __builtin_amdgcn_s_setprio(1);
#pragma unroll
    for (int j2 = 0; j2 < 4; ++j2) {
      const short8 vf0 = *(const short8*)&VL[j2 * 512 + l8];
      const short8 vf1 = *(const short8*)&VL[2048 + j2 * 512 + l8];
      O[j2] = MFMA16(vf0, pf0, O[j2]);
      O[j2] = MFMA16(vf1, pf1, O[j2]);
    }
    l_acc = MFMA16(ones, pf0, l_acc);
    l_acc = MFMA16(ones, pf1, l_acc);
    __builtin_amdgcn_s_setprio(0);

    // ---- rotate the single K/V buffer (T14: late write) ----
    __syncthreads();
    *(short8*)&KL[stoff]        = kn0;
    *(short8*)&KL[2048 + stoff] = kn1;
    *(short8*)&VL[stoff]        = vn0;
    *(short8*)&VL[2048 + stoff] = vn1;
    __syncthreads();
    bc0 = bn0; bc1 = bn1;
  }

  // ---- epilogue: write unnormalized partial O + per-q m,l ----
  const int gg = (b * H_ + h) * 128 + qt;          // [0, 2048)
  const int g  = gg * 2 + half;                    // MP/LP index
  float* Opg = (half ? Op1 : Op0) + (size_t)gg * 1024;
#pragma unroll
  for (int j2 = 0; j2 < 4; ++j2)
    *(f32x4*)&Opg[ln * 64 + j2 * 16 + hb * 4] = O[j2];
  if (hb == 0) {
    MP[g * 16 + ln] = m_run;
    LP[g * 16 + ln] = l_acc[0];
  }
}

// ---------------------------------------------------------------------------
// Kernel 3b: combine the two kv-halves, normalize, write split-bf16 attn-out.
// grid 1024 x 256; thread -> (row, 8 cols).
// ---------------------------------------------------------------------------
__global__ __launch_bounds__(256) void k_comb(
    const float* __restrict__ Op0, const float* __restrict__ Op1,
    const float* __restrict__ MP, const float* __restrict__ LP,
    u16* __restrict__ ah, u16* __restrict__ al)
{
  const int i = blockIdx.x * 256 + threadIdx.x;   // [0, 262144)
  const int row = i >> 5, cg = i & 31;
  const int c0 = cg * 8, h = c0 >> 6, d0 = c0 & 63;
  const int b = row >> 11, nn = row & 2047, qt = nn >> 4, q = nn & 15;
  const int gg = (b * H_ + h) * 128 + qt;
  const int g0 = gg * 2;

  const float m1 = MP[g0 * 16 + q],       m2 = MP[(g0 + 1) * 16 + q];
  const float l1 = LP[g0 * 16 + q],       l2 = LP[(g0 + 1) * 16 + q];
  const float mm = fmaxf(m1, m2);
  const float f1 = exp2f(m1 - mm), f2 = exp2f(m2 - mm);
  const float inv = 1.0f / (l1 * f1 + l2 * f2);

  const float* p1 = Op0 + (size_t)gg * 1024 + q * 64 + d0;
  const float* p2 = Op1 + (size_t)gg * 1024 + q * 64 + d0;
  const f32x4 a1 = *(const f32x4*)p1, b1 = *(const f32x4*)(p1 + 4);
  const f32x4 a2 = *(const f32x4*)p2, b2 = *(const f32x4*)(p2 + 4);

  u16v8 hh, ll;
#pragma unroll
  for (int e = 0; e < 4; ++e) {
    const float v = (a1[e] * f1 + a2[e] * f2) * inv;
    split2(v, &hh.v[e], &ll.v[e]);
  }
#pragma unroll
  for (int e = 0; e < 4; ++e) {
    const float v = (b1[e] * f1 + b2[e] * f2) * inv;
    split2(v, &hh.v[e + 4], &ll.v[e + 4]);
  }
  *(u16v8*)&ah[row * DIMX + c0] = hh;
  *(u16v8*)&al[row * DIMX + c0] = ll;
}

// ---------------------------------------------------------------------------
// Kernel 4: out = aout @ Wout + b_out, LDS-staged. M=8192, N=256, K=256.
// grid (4, 64): colb = bx*64; 2 M-subtiles per block; B hi+lo in 64KB LDS.
// ---------------------------------------------------------------------------
__global__ __launch_bounds__(256) void k_out(
    const u16* __restrict__ ahg, const u16* __restrict__ alg,
    const u16* __restrict__ wh, const u16* __restrict__ wl,
    const float* __restrict__ bout, float* __restrict__ out)
{
  __shared__ __align__(16) u16 BhL[64 * 256];   // 32 KB, swizzled
  __shared__ __align__(16) u16 BlL[64 * 256];   // 32 KB

  const int tid = threadIdx.x;
  const int w = tid >> 6, lane = tid & 63;
  const int ln = lane & 15, hb = lane >> 4;
  const int colb = blockIdx.x * 64;

  // ---- stage B (hi+lo) into LDS ----
  {
    short8 sb[16];
#pragma unroll
    for (int it = 0; it < 8; ++it) {
      const int c = it * 8 + (tid >> 5), k8 = tid & 31;
      sb[it]     = *(const short8*)&wh[(colb + c) * 256 + k8 * 8];
      sb[8 + it] = *(const short8*)&wl[(colb + c) * 256 + k8 * 8];
    }
#pragma unroll
    for (int it = 0; it < 8; ++it) {
      const int c = it * 8 + (tid >> 5), k8 = tid & 31;
      const int le = c * 256 + ((k8 * 8) ^ ((c & 7) << 3));
      *(short8*)&BhL[le] = sb[it];
      *(short8*)&BlL[le] = sb[8 + it];
    }
  }
  __syncthreads();

#pragma unroll
  for (int st = 0; st < 2; ++st) {
    const int mtile = blockIdx.y * 2 + st;
    const int arow = mtile * 64 + w * 16 + ln;

    short8 a_h8[8], a_l8[8];
#pragma unroll
    for (int ks = 0; ks < 8; ++ks) {
      a_h8[ks] = *(const short8*)&ahg[arow * 256 + ks * 32 + hb * 8];
      a_l8[ks] = *(const short8*)&alg[arow * 256 + ks * 32 + hb * 8];
    }

    f32x4 acc[4] = {};
#pragma unroll
    for (int ks = 0; ks < 8; ++ks) {
      const int k0 = ks * 32 + hb * 8;
#pragma unroll
      for (int j = 0; j < 4; ++j) {
        const int c = j * 16 + ln;
        const int le = c * 256 + (k0 ^ ((c & 7) << 3));
        const short8 b_h = *(const short8*)&BhL[le];
        const short8 b_l = *(const short8*)&BlL[le];
        acc[j] = MFMA16(a_h8[ks], b_h, acc[j]);
        acc[j] = MFMA16(a_l8[ks], b_h, acc[j]);
        acc[j] = MFMA16(a_h8[ks], b_l, acc[j]);
      }
    }

    const int mbase = mtile * 64 + w * 16 + hb * 4;
#pragma unroll
    for (int j = 0; j < 4; ++j) {
      const int c = colb + j * 16 + ln;
      const float bb = bout[c];
#pragma unroll
      for (int r = 0; r < 4; ++r)
        out[(mbase + r) * 256 + c] = acc[j][r] + bb;
    }
  }
}

// ---------------------------------------------------------------------------
extern "C" void kernel_launch(void* const* d_in, const int* in_sizes, int n_in,
                              void* d_out, int out_size, void* d_ws, size_t ws_size,
                              hipStream_t stream)
{
  (void)in_sizes; (void)n_in; (void)out_size; (void)ws_size;
  const float* x    = (const float*)d_in[0];
  const int*   mask = (const int*)d_in[1];
  const float* spat = (const float*)d_in[2];
  const float* wq   = (const float*)d_in[3];
  const float* wo   = (const float*)d_in[4];
  const float* bout = (const float*)d_in[5];
  float* out = (float*)d_out;

  char* ws = (char*)d_ws;
  size_t o = 0;
  auto alloc = [&](size_t bytes) -> char* {
    char* p = ws + o;
    o += (bytes + 255) & ~(size_t)255;
    return p;
  };
  u16* xh  = (u16*)alloc((size_t)M_ * 256 * 2);   // 4 MB  \ Op0 alias (8 MB)
  u16* xl  = (u16*)alloc((size_t)M_ * 256 * 2);   // 4 MB  /
  u16* wqh = (u16*)alloc((size_t)768 * 256 * 2);  // 384KB -> MP alias (256KB)
  u16* wql = (u16*)alloc((size_t)768 * 256 * 2);  // 384KB -> LP alias (256KB)
  u16* woh = (u16*)alloc((size_t)256 * 256 * 2);
  u16* wol = (u16*)alloc((size_t)256 * 256 * 2);
  u16* qh  = (u16*)alloc((size_t)16 * N_ * DH_ * 2);
  u16* ql  = (u16*)alloc((size_t)16 * N_ * DH_ * 2);
  u16* kf  = (u16*)alloc((size_t)16 * N_ * DH_ * 2);
  u16* vf  = (u16*)alloc((size_t)16 * N_ * DH_ * 2);
  u16* ah  = (u16*)alloc((size_t)M_ * 256 * 2);
  u16* al  = (u16*)alloc((size_t)M_ * 256 * 2);
  u16* biasF = (u16*)alloc((size_t)4 * 128 * 64 * 512 * 2);  // 33.5 MB fp16

  // Safe scratch aliases (sizes verified, R9-proven):
  //  Op0 (8,388,608 B) <- xh+xl (contiguous, dead after k_qkv)
  //  Op1 (8,388,608 B) <- d_out (fully overwritten by k_out)
  //  MP/LP (262,144 B) <- wqh / wql (393,216 B each, dead after k_qkv)
  float* Op0 = (float*)xh;
  float* Op1 = out;
  float* MP  = (float*)wqh;
  float* LP  = (float*)wql;

  hipLaunchKernelGGL(k_prep, dim3(11264), dim3(256), 0, stream,
                     mask, spat, x, wq, wo, biasF,
                     xh, xl, wqh, wql, woh, wol);
  hipLaunchKernelGGL(k_qkv, dim3(12, 64), dim3(256), 0, stream,
                     xh, xl, wqh, wql, qh, ql, kf, vf);
  hipLaunchKernelGGL(k_attn, dim3(1024), dim3(256), 0, stream,
                     qh, ql, kf, vf, biasF, Op0, Op1, MP, LP);
  hipLaunchKernelGGL(k_comb, dim3(1024), dim3(256), 0, stream,
                     Op0, Op1, MP, LP, ah, al);
  hipLaunchKernelGGL(k_out, dim3(4, 64), dim3(256), 0, stream,
                     ah, al, woh, wol, bout, out);
}

// Round 12
// 118.130 us; speedup vs baseline: 1.0516x; 1.0424x over previous
//
#include <hip/hip_runtime.h>

// ============================================================================
// AttentionWithSpatial: x@Wqkv -> masked/biased 4-head attention -> @Wout+b
// b=4, n=2048, dim=256, heads=4, dhead=64, scale=0.125
//
// R11 post-mortem: barrier-coupled serial chain pins k_attn at 59-65us
// (nothing saturated). R12: BARRIER-FREE k_attn --
//  - K/V fragments read per-wave DIRECTLY from global (no K/V LDS): the 4
//    waves of a block share (b,h,half) so the 4x redundancy is L1-absorbed.
//  - zero __syncthreads in the k-loop; LDS = per-wave Pbuf only (5KB).
//  - K reg-dbuf (1 tile ahead), V issue-early/use-late, bias fp16 acc-init.
//  - swapped PV (O=[d][q], q lane-local rescale/l), defer-max, KVBLK=32.
//  - __launch_bounds__(256,4): VGPR<=128, 16 free-running waves/CU.
//  - k_prep/k_qkv/k_comb/k_out identical to passing R11.
// ============================================================================

#define B_   4
#define N_   2048
#define H_   4
#define DH_  64
#define DIMX 256
#define M_   (B_*N_)   // 8192

#define LOG2E  1.4426950408889634f
#define NEGINF (-1e30f)
#define DEFER_THR 8.0f

typedef __attribute__((ext_vector_type(8))) short short8;
typedef __attribute__((ext_vector_type(4))) float f32x4;
typedef unsigned short u16;
typedef unsigned int   u32;

#define MFMA16(a,b,c) __builtin_amdgcn_mfma_f32_16x16x32_bf16((a),(b),(c),0,0,0)

__device__ __forceinline__ u16 f2bf(float f) {
  u32 u = __builtin_bit_cast(u32, f);
  u += 0x7fffu + ((u >> 16) & 1u);   // RNE
  return (u16)(u >> 16);
}
__device__ __forceinline__ float bf2f(u16 h) {
  u32 u = ((u32)h) << 16;
  return __builtin_bit_cast(float, u);
}
__device__ __forceinline__ void split2(float f, u16* hi, u16* lo) {
  u16 h = f2bf(f);
  *hi = h;
  *lo = f2bf(f - bf2f(h));
}
__device__ __forceinline__ u32 cvtpk(float lo, float hi) {
  u32 r;
  asm("v_cvt_pk_bf16_f32 %0, %1, %2" : "=v"(r) : "v"(lo), "v"(hi));
  return r;
}

struct u16v4 { u16 a, b, c, d; };
struct u16v8 { u16 v[8]; };

// ---------------------------------------------------------------------------
// Kernel 1 (fused prep):
//  blocks [0,8192): bias prefuse  mask? spat*log2e : -1e4  -> fp16 frag-major
//  blocks [8192,11264): x -> xh/xl split; Wqkv/Wout transpose+split
// ---------------------------------------------------------------------------
__global__ __launch_bounds__(256) void k_prep(
    const int* __restrict__ mask, const float* __restrict__ spat,
    const float* __restrict__ x, const float* __restrict__ wq,
    const float* __restrict__ wo,
    u16* __restrict__ biasF,
    u16* __restrict__ xh, u16* __restrict__ xl,
    u16* __restrict__ wqh, u16* __restrict__ wql,
    u16* __restrict__ woh, u16* __restrict__ wol)
{
  if (blockIdx.x < 8192) {
    const int r = blockIdx.x * 256 + threadIdx.x;     // [0, 2097152)
    const int lane = r & 63;
    const int kt = (r >> 6) & 63;
    const int qt = (r >> 12) & 127;
    const int b  = r >> 19;
    const int ln = lane & 15, hb = lane >> 4;
    const int q  = qt * 16 + ln;
    const int c0 = kt * 32 + hb * 4;
    const int base = (b * N_ + q) * N_ + c0;

    const int4   m0 = *(const int4*)&mask[base];
    const int4   m1 = *(const int4*)&mask[base + 16];
    const float4 s0 = *(const float4*)&spat[base];
    const float4 s1 = *(const float4*)&spat[base + 16];

    const float NB = -10000.0f;
    u16v8 o;
    o.v[0] = __builtin_bit_cast(u16, (_Float16)(m0.x ? s0.x * LOG2E : NB));
    o.v[1] = __builtin_bit_cast(u16, (_Float16)(m0.y ? s0.y * LOG2E : NB));
    o.v[2] = __builtin_bit_cast(u16, (_Float16)(m0.z ? s0.z * LOG2E : NB));
    o.v[3] = __builtin_bit_cast(u16, (_Float16)(m0.w ? s0.w * LOG2E : NB));
    o.v[4] = __builtin_bit_cast(u16, (_Float16)(m1.x ? s1.x * LOG2E : NB));
    o.v[5] = __builtin_bit_cast(u16, (_Float16)(m1.y ? s1.y * LOG2E : NB));
    o.v[6] = __builtin_bit_cast(u16, (_Float16)(m1.z ? s1.z * LOG2E : NB));
    o.v[7] = __builtin_bit_cast(u16, (_Float16)(m1.w ? s1.w * LOG2E : NB));
    *(u16v8*)&biasF[(size_t)r * 8] = o;
    return;
  }

  const int NX4 = (M_ * DIMX) / 4;  // 524288
  const int NWQ = 768 * 256;        // 196608
  const int NWO = 256 * 256;        // 65536
  int i = (blockIdx.x - 8192) * 256 + threadIdx.x;
  if (i < NX4) {
    const float4 v = ((const float4*)x)[i];
    u16v4 hv, lv;
    split2(v.x, &hv.a, &lv.a);
    split2(v.y, &hv.b, &lv.b);
    split2(v.z, &hv.c, &lv.c);
    split2(v.w, &hv.d, &lv.d);
    ((u16v4*)xh)[i] = hv;
    ((u16v4*)xl)[i] = lv;
  } else if (i < NX4 + NWQ) {
    int j = i - NX4;
    int c = j >> 8, k = j & 255;            // out layout [c][k]
    split2(wq[k * 768 + c], &wqh[j], &wql[j]);
  } else if (i < NX4 + NWQ + NWO) {
    int j = i - NX4 - NWQ;
    int c = j >> 8, k = j & 255;
    split2(wo[k * 256 + c], &woh[j], &wol[j]);
  }
}

// ---------------------------------------------------------------------------
// Kernel 2: QKV GEMM, LDS-staged. M=8192, N=768, K=256. grid (12, 64).
// B tile (hi+lo) staged once in 64KB LDS, XOR-swizzled; 2 M-subtiles/block;
// 16 A loads upfront per subtile; MFMA fed from LDS.
// ---------------------------------------------------------------------------
__global__ __launch_bounds__(256) void k_qkv(
    const u16* __restrict__ xh, const u16* __restrict__ xl,
    const u16* __restrict__ wh, const u16* __restrict__ wl,
    u16* __restrict__ qh, u16* __restrict__ ql,
    u16* __restrict__ kf, u16* __restrict__ vf)
{
  __shared__ __align__(16) u16 BhL[64 * 256];   // 32 KB, swizzled
  __shared__ __align__(16) u16 BlL[64 * 256];   // 32 KB

  const int tid = threadIdx.x;
  const int w = tid >> 6, lane = tid & 63;
  const int ln = lane & 15, hb = lane >> 4;
  const int colb = blockIdx.x * 64;

  // ---- stage B (hi+lo) into LDS, reg-batched, coalesced ----
  {
    short8 sb[16];
#pragma unroll
    for (int it = 0; it < 8; ++it) {
      const int c = it * 8 + (tid >> 5), k8 = tid & 31;
      sb[it]     = *(const short8*)&wh[(colb + c) * 256 + k8 * 8];
      sb[8 + it] = *(const short8*)&wl[(colb + c) * 256 + k8 * 8];
    }
#pragma unroll
    for (int it = 0; it < 8; ++it) {
      const int c = it * 8 + (tid >> 5), k8 = tid & 31;
      const int le = c * 256 + ((k8 * 8) ^ ((c & 7) << 3));
      *(short8*)&BhL[le] = sb[it];
      *(short8*)&BlL[le] = sb[8 + it];
    }
  }
  __syncthreads();

#pragma unroll
  for (int st = 0; st < 2; ++st) {
    const int mtile = blockIdx.y * 2 + st;
    const int arow = mtile * 64 + w * 16 + ln;

    short8 a_h8[8], a_l8[8];
#pragma unroll
    for (int ks = 0; ks < 8; ++ks) {
      a_h8[ks] = *(const short8*)&xh[arow * 256 + ks * 32 + hb * 8];
      a_l8[ks] = *(const short8*)&xl[arow * 256 + ks * 32 + hb * 8];
    }

    f32x4 acc[4] = {};
#pragma unroll
    for (int ks = 0; ks < 8; ++ks) {
      const int k0 = ks * 32 + hb * 8;
#pragma unroll
      for (int j = 0; j < 4; ++j) {
        const int c = j * 16 + ln;
        const int le = c * 256 + (k0 ^ ((c & 7) << 3));
        const short8 b_h = *(const short8*)&BhL[le];
        const short8 b_l = *(const short8*)&BlL[le];
        acc[j] = MFMA16(a_h8[ks], b_h, acc[j]);
        acc[j] = MFMA16(a_l8[ks], b_h, acc[j]);
        acc[j] = MFMA16(a_h8[ks], b_l, acc[j]);
      }
    }

    const int mbase = mtile * 64 + w * 16 + hb * 4;
#pragma unroll
    for (int j = 0; j < 4; ++j) {
      const int c = colb + j * 16 + ln;
      const int which = c >> 8;        // 0=q 1=k 2=v
      const int hd = c & 255;
      const int hh = hd >> 6, d = hd & 63;
#pragma unroll
      for (int r = 0; r < 4; ++r) {
        const int m = mbase + r;
        const int bb = m >> 11, nn = m & 2047;
        const int bh = bb * H_ + hh;
        float v = acc[j][r];
        if (which == 0) {
          const int off = (bh * N_ + nn) * DH_ + d;
          v *= (0.125f * LOG2E);                 // scale + exp2-domain fold
          split2(v, &qh[off], &ql[off]);
        } else if (which == 1) {
          const int ktile = nn >> 5, jj = (nn >> 4) & 1, lnn = nn & 15;
          const int kc = d >> 5, hbb = (d >> 3) & 3, e = d & 7;
          const int off = (bh * 64 + ktile) * 2048 + (kc * 2 + jj) * 512
                        + (hbb * 16 + lnn) * 8 + e;
          kf[off] = f2bf(v);
        } else {
          const int ktile = nn >> 5, hbb = (nn >> 3) & 3, e = nn & 7;
          const int j2 = d >> 4, lnn = d & 15;
          const int off = (bh * 64 + ktile) * 2048 + j2 * 512
                        + (hbb * 16 + lnn) * 8 + e;
          vf[off] = f2bf(v);
        }
      }
    }
  }
}

// ---------------------------------------------------------------------------
// Kernel 3: flash attention partials, KV-split=2, BARRIER-FREE. grid 1024:
// bid = qq*32 + bh*2 + half; 4 waves = 4 q-tiles of SAME (b,h,half):
// K/V fragment loads go straight global->reg (4x wave redundancy absorbed
// by L1; lines shared within the block). K reg-dbuf one tile ahead; V loaded
// at iter start, used at iter end; bias fp16 = accumulator init.
// Swapped PV: O[d][q], q=ln lane-local -> rescale & l without cross-lane.
// LDS = per-wave P-exchange only (wave-synchronous). No __syncthreads.
// ---------------------------------------------------------------------------
__global__ __launch_bounds__(256, 4) void k_attn(
    const u16* __restrict__ qhg, const u16* __restrict__ qlg,
    const u16* __restrict__ kfg, const u16* __restrict__ vfg,
    const u16* __restrict__ biasF,
    float* __restrict__ Op0, float* __restrict__ Op1,
    float* __restrict__ MP, float* __restrict__ LP)
{
  __shared__ __align__(16) u32 Pbuf[4][320];   // 5 KB: per-wave P exchange

  const int bid = blockIdx.x;
  const int half = bid & 1;
  const int bh = (bid >> 1) & 15;
  const int qq = bid >> 5;
  const int b = bh >> 2, h = bh & 3;
  const int kt0 = half * 32;

  const int tid = threadIdx.x;
  const int w = tid >> 6, lane = tid & 63;
  const int qt = qq * 4 + w;                   // this wave's q-tile [0,128)
  const int ln = lane & 15, hb = lane >> 4;

  // ---- Q fragments (pre-scaled by 0.125*log2e), hi/lo ----
  short8 qfh[2], qfl[2];
  {
    const int base = ((b * H_ + h) * N_ + qt * 16 + ln) * DH_;
    qfh[0] = *(const short8*)&qhg[base + hb * 8];
    qfh[1] = *(const short8*)&qhg[base + 32 + hb * 8];
    qfl[0] = *(const short8*)&qlg[base + hb * 8];
    qfl[1] = *(const short8*)&qlg[base + 32 + hb * 8];
  }

  // per-lane fragment bases (l8 folded in; per-tile offset = kt*2048)
  const u16* Kt0 = kfg + (size_t)((b * H_ + h) * 64) * 2048 + lane * 8;
  const u16* Vt0 = vfg + (size_t)((b * H_ + h) * 64) * 2048 + lane * 8;
  const u16* Bt0 = biasF + (size_t)((b * 128 + qt) * 64) * 512 + lane * 8;

  short8 ones;
#pragma unroll
  for (int i = 0; i < 8; ++i) ones[i] = (short)0x3F80;   // bf16 1.0

  f32x4 O[4] = {};        // lane holds O[d=j2*16+hb*4+r][q=ln]
  f32x4 l_acc = {};       // all entries = l(q=ln)
  float m_run = NEGINF;   // per-lane (q=ln)
  u32* Pw = &Pbuf[w][0];

  short8 Ka[4], Kb[4], bc, bn;

  // ---- prologue: K tile kt0 + bias kt0 ----
#pragma unroll
  for (int i = 0; i < 4; ++i)
    Ka[i] = *(const short8*)&Kt0[kt0 * 2048 + i * 512];
  bc = *(const short8*)&Bt0[kt0 * 512];

  auto body = [&](short8 (&Kc)[4], short8 (&Kn)[4],
                  short8& bcur, short8& bnxt, int ktc, int ktn) {
    // ---- issue loads: V for THIS tile (used late), K+bias for NEXT ----
    short8 Vc[4];
#pragma unroll
    for (int i = 0; i < 4; ++i)
      Vc[i] = *(const short8*)&Vt0[ktc * 2048 + i * 512];
#pragma unroll
    for (int i = 0; i < 4; ++i)
      Kn[i] = *(const short8*)&Kt0[ktn * 2048 + i * 512];
    bnxt = *(const short8*)&Bt0[ktn * 512];

    // ---- swapped QK^T, accumulator init = bias ----
    // dots[j][r] = S[k = j*16 + hb*4 + r][q = ln]
    f32x4 dots[2];
#pragma unroll
    for (int j = 0; j < 2; ++j)
#pragma unroll
      for (int r = 0; r < 4; ++r)
        dots[j][r] = (float)__builtin_bit_cast(_Float16, (u16)bcur[j * 4 + r]);
    __builtin_amdgcn_s_setprio(1);
#pragma unroll
    for (int kc = 0; kc < 2; ++kc)
#pragma unroll
      for (int j = 0; j < 2; ++j) {
        dots[j] = MFMA16(Kc[kc * 2 + j], qfh[kc], dots[j]);
        dots[j] = MFMA16(Kc[kc * 2 + j], qfl[kc], dots[j]);
      }
    __builtin_amdgcn_s_setprio(0);

    // ---- per-q online softmax (q=ln), defer-max THR=8 ----
    float pmax = fmaxf(fmaxf(fmaxf(dots[0][0], dots[0][1]),
                             fmaxf(dots[0][2], dots[0][3])),
                       fmaxf(fmaxf(dots[1][0], dots[1][1]),
                             fmaxf(dots[1][2], dots[1][3])));
    pmax = fmaxf(pmax, __shfl_xor(pmax, 16));
    pmax = fmaxf(pmax, __shfl_xor(pmax, 32));
    if (__any(pmax > m_run + DEFER_THR)) {
      const float mn = fmaxf(m_run, pmax);
      const float fac = exp2f(m_run - mn);     // lane-local (q=ln)
      m_run = mn;
#pragma unroll
      for (int j2 = 0; j2 < 4; ++j2) {
        O[j2][0] *= fac; O[j2][1] *= fac; O[j2][2] *= fac; O[j2][3] *= fac;
      }
      l_acc[0] *= fac; l_acc[1] *= fac; l_acc[2] *= fac; l_acc[3] *= fac;
    }
    float p[2][4];
#pragma unroll
    for (int j = 0; j < 2; ++j)
#pragma unroll
      for (int r = 0; r < 4; ++r)
        p[j][r] = exp2f(dots[j][r] - m_run);

    // ---- P-exchange via per-wave LDS (wave-synchronous, no barrier) ----
#pragma unroll
    for (int j = 0; j < 2; ++j) {
      uint2 wv;
      wv.x = cvtpk(p[j][0], p[j][1]);
      wv.y = cvtpk(p[j][2], p[j][3]);
      *(uint2*)&Pw[ln * 20 + j * 8 + hb * 2] = wv;   // k = j*16+hb*4+{0..3}
    }
    const short8 pf = *(const short8*)&Pw[ln * 20 + hb * 4];  // P[k=hb*8+e][q=ln]

    // ---- swapped PV: O += V^T_A x P_B ; l += ones x P ----
    __builtin_amdgcn_s_setprio(1);
#pragma unroll
    for (int j2 = 0; j2 < 4; ++j2)
      O[j2] = MFMA16(Vc[j2], pf, O[j2]);
    l_acc = MFMA16(ones, pf, l_acc);
    __builtin_amdgcn_s_setprio(0);
  };

  for (int it = 0; it < 16; ++it) {
    const int t  = kt0 + 2 * it;
    const int t2 = kt0 + ((2 * it + 2) & 31);  // wraps on last prefetch
    body(Ka, Kb, bc, bn, t,     t + 1);
    body(Kb, Ka, bn, bc, t + 1, t2);
  }

  // ---- epilogue: write unnormalized partial O + per-q m,l ----
  const int gg = (b * H_ + h) * 128 + qt;          // [0, 2048)
  const int g  = gg * 2 + half;                    // MP/LP index
  float* Opg = (half ? Op1 : Op0) + (size_t)gg * 1024;
#pragma unroll
  for (int j2 = 0; j2 < 4; ++j2)
    *(f32x4*)&Opg[ln * 64 + j2 * 16 + hb * 4] = O[j2];
  if (hb == 0) {
    MP[g * 16 + ln] = m_run;
    LP[g * 16 + ln] = l_acc[0];
  }
}

// ---------------------------------------------------------------------------
// Kernel 3b: combine the two kv-halves, normalize, write split-bf16 attn-out.
// grid 1024 x 256; thread -> (row, 8 cols).
// ---------------------------------------------------------------------------
__global__ __launch_bounds__(256) void k_comb(
    const float* __restrict__ Op0, const float* __restrict__ Op1,
    const float* __restrict__ MP, const float* __restrict__ LP,
    u16* __restrict__ ah, u16* __restrict__ al)
{
  const int i = blockIdx.x * 256 + threadIdx.x;   // [0, 262144)
  const int row = i >> 5, cg = i & 31;
  const int c0 = cg * 8, h = c0 >> 6, d0 = c0 & 63;
  const int b = row >> 11, nn = row & 2047, qt = nn >> 4, q = nn & 15;
  const int gg = (b * H_ + h) * 128 + qt;
  const int g0 = gg * 2;

  const float m1 = MP[g0 * 16 + q],       m2 = MP[(g0 + 1) * 16 + q];
  const float l1 = LP[g0 * 16 + q],       l2 = LP[(g0 + 1) * 16 + q];
  const float mm = fmaxf(m1, m2);
  const float f1 = exp2f(m1 - mm), f2 = exp2f(m2 - mm);
  const float inv = 1.0f / (l1 * f1 + l2 * f2);

  const float* p1 = Op0 + (size_t)gg * 1024 + q * 64 + d0;
  const float* p2 = Op1 + (size_t)gg * 1024 + q * 64 + d0;
  const f32x4 a1 = *(const f32x4*)p1, b1 = *(const f32x4*)(p1 + 4);
  const f32x4 a2 = *(const f32x4*)p2, b2 = *(const f32x4*)(p2 + 4);

  u16v8 hh, ll;
#pragma unroll
  for (int e = 0; e < 4; ++e) {
    const float v = (a1[e] * f1 + a2[e] * f2) * inv;
    split2(v, &hh.v[e], &ll.v[e]);
  }
#pragma unroll
  for (int e = 0; e < 4; ++e) {
    const float v = (b1[e] * f1 + b2[e] * f2) * inv;
    split2(v, &hh.v[e + 4], &ll.v[e + 4]);
  }
  *(u16v8*)&ah[row * DIMX + c0] = hh;
  *(u16v8*)&al[row * DIMX + c0] = ll;
}

// ---------------------------------------------------------------------------
// Kernel 4: out = aout @ Wout + b_out, LDS-staged. M=8192, N=256, K=256.
// grid (4, 64): colb = bx*64; 2 M-subtiles per block; B hi+lo in 64KB LDS.
// ---------------------------------------------------------------------------
__global__ __launch_bounds__(256) void k_out(
    const u16* __restrict__ ahg, const u16* __restrict__ alg,
    const u16* __restrict__ wh, const u16* __restrict__ wl,
    const float* __restrict__ bout, float* __restrict__ out)
{
  __shared__ __align__(16) u16 BhL[64 * 256];   // 32 KB, swizzled
  __shared__ __align__(16) u16 BlL[64 * 256];   // 32 KB

  const int tid = threadIdx.x;
  const int w = tid >> 6, lane = tid & 63;
  const int ln = lane & 15, hb = lane >> 4;
  const int colb = blockIdx.x * 64;

  // ---- stage B (hi+lo) into LDS ----
  {
    short8 sb[16];
#pragma unroll
    for (int it = 0; it < 8; ++it) {
      const int c = it * 8 + (tid >> 5), k8 = tid & 31;
      sb[it]     = *(const short8*)&wh[(colb + c) * 256 + k8 * 8];
      sb[8 + it] = *(const short8*)&wl[(colb + c) * 256 + k8 * 8];
    }
#pragma unroll
    for (int it = 0; it < 8; ++it) {
      const int c = it * 8 + (tid >> 5), k8 = tid & 31;
      const int le = c * 256 + ((k8 * 8) ^ ((c & 7) << 3));
      *(short8*)&BhL[le] = sb[it];
      *(short8*)&BlL[le] = sb[8 + it];
    }
  }
  __syncthreads();

#pragma unroll
  for (int st = 0; st < 2; ++st) {
    const int mtile = blockIdx.y * 2 + st;
    const int arow = mtile * 64 + w * 16 + ln;

    short8 a_h8[8], a_l8[8];
#pragma unroll
    for (int ks = 0; ks < 8; ++ks) {
      a_h8[ks] = *(const short8*)&ahg[arow * 256 + ks * 32 + hb * 8];
      a_l8[ks] = *(const short8*)&alg[arow * 256 + ks * 32 + hb * 8];
    }

    f32x4 acc[4] = {};
#pragma unroll
    for (int ks = 0; ks < 8; ++ks) {
      const int k0 = ks * 32 + hb * 8;
#pragma unroll
      for (int j = 0; j < 4; ++j) {
        const int c = j * 16 + ln;
        const int le = c * 256 + (k0 ^ ((c & 7) << 3));
        const short8 b_h = *(const short8*)&BhL[le];
        const short8 b_l = *(const short8*)&BlL[le];
        acc[j] = MFMA16(a_h8[ks], b_h, acc[j]);
        acc[j] = MFMA16(a_l8[ks], b_h, acc[j]);
        acc[j] = MFMA16(a_h8[ks], b_l, acc[j]);
      }
    }

    const int mbase = mtile * 64 + w * 16 + hb * 4;
#pragma unroll
    for (int j = 0; j < 4; ++j) {
      const int c = colb + j * 16 + ln;
      const float bb = bout[c];
#pragma unroll
      for (int r = 0; r < 4; ++r)
        out[(mbase + r) * 256 + c] = acc[j][r] + bb;
    }
  }
}

// ---------------------------------------------------------------------------
extern "C" void kernel_launch(void* const* d_in, const int* in_sizes, int n_in,
                              void* d_out, int out_size, void* d_ws, size_t ws_size,
                              hipStream_t stream)
{
  (void)in_sizes; (void)n_in; (void)out_size; (void)ws_size;
  const float* x    = (const float*)d_in[0];
  const int*   mask = (const int*)d_in[1];
  const float* spat = (const float*)d_in[2];
  const float* wq   = (const float*)d_in[3];
  const float* wo   = (const float*)d_in[4];
  const float* bout = (const float*)d_in[5];
  float* out = (float*)d_out;

  char* ws = (char*)d_ws;
  size_t o = 0;
  auto alloc = [&](size_t bytes) -> char* {
    char* p = ws + o;
    o += (bytes + 255) & ~(size_t)255;
    return p;
  };
  u16* xh  = (u16*)alloc((size_t)M_ * 256 * 2);   // 4 MB  \ Op0 alias (8 MB)
  u16* xl  = (u16*)alloc((size_t)M_ * 256 * 2);   // 4 MB  /
  u16* wqh = (u16*)alloc((size_t)768 * 256 * 2);  // 384KB -> MP alias (256KB)
  u16* wql = (u16*)alloc((size_t)768 * 256 * 2);  // 384KB -> LP alias (256KB)
  u16* woh = (u16*)alloc((size_t)256 * 256 * 2);
  u16* wol = (u16*)alloc((size_t)256 * 256 * 2);
  u16* qh  = (u16*)alloc((size_t)16 * N_ * DH_ * 2);
  u16* ql  = (u16*)alloc((size_t)16 * N_ * DH_ * 2);
  u16* kf  = (u16*)alloc((size_t)16 * N_ * DH_ * 2);
  u16* vf  = (u16*)alloc((size_t)16 * N_ * DH_ * 2);
  u16* ah  = (u16*)alloc((size_t)M_ * 256 * 2);
  u16* al  = (u16*)alloc((size_t)M_ * 256 * 2);
  u16* biasF = (u16*)alloc((size_t)4 * 128 * 64 * 512 * 2);  // 33.5 MB fp16

  // Safe scratch aliases (sizes verified, R9-proven):
  //  Op0 (8,388,608 B) <- xh+xl (contiguous, dead after k_qkv)
  //  Op1 (8,388,608 B) <- d_out (fully overwritten by k_out)
  //  MP/LP (262,144 B) <- wqh / wql (393,216 B each, dead after k_qkv)
  float* Op0 = (float*)xh;
  float* Op1 = out;
  float* MP  = (float*)wqh;
  float* LP  = (float*)wql;

  hipLaunchKernelGGL(k_prep, dim3(11264), dim3(256), 0, stream,
                     mask, spat, x, wq, wo, biasF,
                     xh, xl, wqh, wql, woh, wol);
  hipLaunchKernelGGL(k_qkv, dim3(12, 64), dim3(256), 0, stream,
                     xh, xl, wqh, wql, qh, ql, kf, vf);
  hipLaunchKernelGGL(k_attn, dim3(1024), dim3(256), 0, stream,
                     qh, ql, kf, vf, biasF, Op0, Op1, MP, LP);
  hipLaunchKernelGGL(k_comb, dim3(1024), dim3(256), 0, stream,
                     Op0, Op1, MP, LP, ah, al);
  hipLaunchKernelGGL(k_out, dim3(4, 64), dim3(256), 0, stream,
                     ah, al, woh, wol, bout, out);
}